// Round 1
// 950.042 us; speedup vs baseline: 1.0331x; 1.0331x over previous
//
#include <hip/hip_runtime.h>

typedef unsigned short u16;
typedef unsigned int u32;
typedef __attribute__((ext_vector_type(4))) u16 u16x4;
typedef __attribute__((ext_vector_type(8))) __bf16 bf16x8;
typedef __attribute__((ext_vector_type(4))) float floatx4;

#define INV_BN 0.9999950000374997f
#define IN0 2176
#define N0EXT 12416  // 12288 expert cols + 56 gate cols + 72 pad
#define N1EXT 2176   // 2048 expert cols + 16 gate cols + 112 pad

__device__ __forceinline__ float b2f(u16 u) {
  return __builtin_bit_cast(float, (u32)u << 16);
}
__device__ __forceinline__ u16 f2b(float f) {
  u32 x = __builtin_bit_cast(u32, f);
  return (u16)((x + 0x7fffu + ((x >> 16) & 1u)) >> 16);
}

// ---------------- input build: embed gather + numerical linear -> X0 ---------------
__global__ __launch_bounds__(256) void input_build(
    const int* __restrict__ cat, const float* __restrict__ table,
    const float* __restrict__ xn, const float* __restrict__ W,
    const float* __restrict__ bias, u16* __restrict__ X0) {
  int x = blockIdx.x, tid = threadIdx.x;
  if (x < 8192) {
    int idx = x * 256 + tid;  // over B*F*32 float4-groups
    int d4 = idx & 31;
    int bf = idx >> 5;
    int f = bf & 15;
    int b = bf >> 4;
    long row = (long)cat[bf] + (long)f * 50000;
    float4 v = *((const float4*)(table + row * 128) + d4);
    u16x4 o = {f2b(v.x), f2b(v.y), f2b(v.z), f2b(v.w)};
    *(u16x4*)(X0 + (long)b * IN0 + f * 128 + d4 * 4) = o;
  } else {
    int idx = (x - 8192) * 256 + tid;  // B*128
    int o = idx & 127;
    int b = idx >> 7;
    float acc = bias[o];
    const float* xr = xn + b * 63;
    for (int k = 0; k < 63; k++) acc = fmaf(xr[k], W[k * 128 + o], acc);
    X0[(long)b * IN0 + 2048 + o] = f2b(acc);
  }
}

// ---------------- all expert-weight repacks in one launch --------------------------
// src [E][K][O] f32 -> dst bf16 row (nBase+e*O+o), k-contiguous, col-scaled by INV*g.
__global__ __launch_bounds__(256) void repack_w_all(
    const float* __restrict__ te0W, const float* __restrict__ te0g,
    const float* __restrict__ se0W, const float* __restrict__ se0g,
    const float* __restrict__ te1W, const float* __restrict__ te1g,
    const float* __restrict__ se1W, const float* __restrict__ se1g,
    const float* __restrict__ tw0W, const float* __restrict__ tw0g,
    u16* __restrict__ W0, u16* __restrict__ W1, u16* __restrict__ TW0) {
  int z = blockIdx.z;
  const float *src, *gsc;
  u16* dst;
  int K, O, nBase, e, xm, ym;
  if (z < 16) {
    e = z; src = te0W; gsc = te0g; dst = W0; K = 2176; O = 512; nBase = 0; xm = 68; ym = 16;
  } else if (z < 24) {
    e = z - 16; src = se0W; gsc = se0g; dst = W0; K = 2176; O = 512; nBase = 8192; xm = 68; ym = 16;
  } else if (z < 40) {
    e = z - 24; src = te1W; gsc = te1g; dst = W1; K = 512; O = 256;
    nBase = (e < 8) ? 0 : (N1EXT - 2048); xm = 16; ym = 8;
  } else if (z < 48) {
    e = z - 40; src = se1W; gsc = se1g; dst = W1; K = 512; O = 256; nBase = 2 * N1EXT; xm = 16; ym = 8;
  } else {
    e = z - 48; src = tw0W; gsc = tw0g; dst = TW0; K = 256; O = 128; nBase = 0; xm = 8; ym = 4;
  }
  if (blockIdx.x >= (u32)xm || blockIdx.y >= (u32)ym) return;
  __shared__ float tile[32][33];
  int k0 = blockIdx.x * 32, o0 = blockIdx.y * 32;
  int tx = threadIdx.x & 31, ty = threadIdx.x >> 5;
  const float* S = src + (long)e * K * O;
#pragma unroll
  for (int r = 0; r < 32; r += 8)
    tile[ty + r][tx] = S[(long)(k0 + ty + r) * O + o0 + tx];
  __syncthreads();
#pragma unroll
  for (int r = 0; r < 32; r += 8) {
    int o = o0 + ty + r;
    float s = INV_BN * gsc[e * O + o];
    dst[(long)(nBase + e * O + o) * K + k0 + tx] = f2b(tile[tx][ty + r] * s);
  }
}

// ---------------- all small setup work in one launch -------------------------------
__global__ __launch_bounds__(256) void setup_small(
    const float* __restrict__ tg0W, const float* __restrict__ tg0b,
    const float* __restrict__ sg0W, const float* __restrict__ sg0b,
    const float* __restrict__ tg1W, const float* __restrict__ tg1b,
    const float* __restrict__ te0b, const float* __restrict__ te0g, const float* __restrict__ te0be,
    const float* __restrict__ se0b, const float* __restrict__ se0g, const float* __restrict__ se0be,
    const float* __restrict__ te1b, const float* __restrict__ te1g, const float* __restrict__ te1be,
    const float* __restrict__ se1b, const float* __restrict__ se1g, const float* __restrict__ se1be,
    const float* __restrict__ tw0b, const float* __restrict__ tw0g, const float* __restrict__ tw0be,
    const float* __restrict__ tw1W, const float* __restrict__ tw1b,
    const float* __restrict__ tw1g, const float* __restrict__ tw1be,
    u16* __restrict__ W0, u16* __restrict__ W1, u16* __restrict__ TW1,
    float* __restrict__ bias0, float* __restrict__ bias1,
    float* __restrict__ biasT0, float* __restrict__ biasT1) {
  int x = blockIdx.x, tid = threadIdx.x;
  if (x < 128) {  // layer-0 gate rows (W0 rows 12288..12415)
    int g = x;
    u16* dst = W0 + (long)(12288 + g) * IN0;
    for (int k = tid; k < IN0; k += 256) {
      float v;
      if (g < 32) {
        int t = g >> 4, j = g & 15;
        v = tg0W[(long)t * IN0 * 16 + k * 16 + j];
      } else if (g < 56) {
        v = sg0W[k * 24 + (g - 32)];
      } else {
        v = 0.f;
      }
      dst[k] = f2b(v);
    }
    if (tid == 0)
      bias0[12288 + g] = g < 32 ? tg0b[g] : (g < 56 ? sg0b[g - 32] : 0.f);
  } else if (x < 512) {  // layer-1 gate rows
    int i = x - 128;
    int z = i >> 7, g = i & 127;
    u16* dst = W1 + (long)z * N1EXT * 512 + (long)(2048 + g) * 512;
    for (int k = tid; k < 512; k += 256) {
      float v = (z < 2 && g < 16) ? tg1W[(long)z * 512 * 16 + k * 16 + g] : 0.f;
      dst[k] = f2b(v);
    }
    if (tid == 0)
      bias1[z * N1EXT + 2048 + g] = (z < 2 && g < 16) ? tg1b[z * 16 + g] : 0.f;
  } else if (x < 640) {  // tower layer-1 weight repack [2][128k][64o] -> [2][128n][128k]
    int idx = (x - 512) * 256 + tid;  // [0, 32768)
    int z = idx >> 14, rem = idx & 16383, n = rem >> 7, k = rem & 127;
    float v = 0.f;
    if (n < 64) v = tw1W[(long)z * 128 * 64 + k * 64 + n] * INV_BN * tw1g[z * 64 + n];
    TW1[(long)z * 128 * 128 + n * 128 + k] = f2b(v);
    if (k == 0)
      biasT1[z * 128 + n] =
          (n < 64) ? tw1b[z * 64 + n] * INV_BN * tw1g[z * 64 + n] + tw1be[z * 64 + n] : 0.f;
  } else if (x < 688) {  // bias0 expert part
    int i = (x - 640) * 256 + tid;  // < 12288
    if (i < 8192) bias0[i] = te0b[i] * INV_BN * te0g[i] + te0be[i];
    else {
      int r = i - 8192;
      bias0[i] = se0b[r] * INV_BN * se0g[r] + se0be[r];
    }
  } else if (x < 712) {  // bias1 expert part
    int j = (x - 688) * 256 + tid;  // < 6144
    int z = j >> 11, r = j & 2047;
    float v;
    if (z < 2) v = te1b[z * 2048 + r] * INV_BN * te1g[z * 2048 + r] + te1be[z * 2048 + r];
    else v = se1b[r] * INV_BN * se1g[r] + se1be[r];
    bias1[z * N1EXT + r] = v;
  } else {  // biasT0
    biasT0[tid] = tw0b[tid] * INV_BN * tw0g[tid] + tw0be[tid];
  }
}

// ---------------- m97-style bf16 GEMM body (kept for 128-col gate panels) ----------
// A [M][K] bf16 row-major, Bw [N][K] bf16 (n-major), C [M][N] bf16.
// C[m][n] = (n<reluN ? relu : id)(sum_k A.B + bias[n]). 128x128 tile, BK=32.
__device__ __forceinline__ void gemm_body(
    const u16* __restrict__ A, const u16* __restrict__ Bw, u16* __restrict__ C,
    const float* __restrict__ bias, int N, int K, int reluN, int yOff) {
  __shared__ u16 As[128 * 32];
  __shared__ u16 Bs[128 * 32];
  int tid = threadIdx.x;
  int m0 = blockIdx.x * 128, n0 = (blockIdx.y + yOff) * 128;
  int l = tid & 63, w = tid >> 6;
  int wm = (w >> 1) * 64, wn = (w & 1) * 64;

  const u16* aS0 = A + (long)(m0 + (tid >> 2)) * K + (tid & 3) * 8;
  const u16* aS1 = A + (long)(m0 + 64 + (tid >> 2)) * K + (tid & 3) * 8;
  const u16* bS0 = Bw + (long)(n0 + (tid >> 2)) * K + (tid & 3) * 8;
  const u16* bS1 = Bw + (long)(n0 + 64 + (tid >> 2)) * K + (tid & 3) * 8;
  u16* aD0 = As + tid * 8;
  u16* aD1 = As + (256 + tid) * 8;
  u16* bD0 = Bs + tid * 8;
  u16* bD1 = Bs + (256 + tid) * 8;

  floatx4 acc[4][4] = {};

  int aOff[4], bOff[4];
#pragma unroll
  for (int i = 0; i < 4; i++) {
    aOff[i] = (wm + i * 16 + (l & 15)) * 32 + (l >> 4) * 8;
    bOff[i] = (wn + i * 16 + (l & 15)) * 32 + (l >> 4) * 8;
  }

  for (int k0 = 0; k0 < K; k0 += 32) {
    __builtin_amdgcn_global_load_lds((const __attribute__((address_space(1))) u16*)aS0,
                                     (__attribute__((address_space(3))) u16*)aD0, 16, 0, 0);
    __builtin_amdgcn_global_load_lds((const __attribute__((address_space(1))) u16*)aS1,
                                     (__attribute__((address_space(3))) u16*)aD1, 16, 0, 0);
    __builtin_amdgcn_global_load_lds((const __attribute__((address_space(1))) u16*)bS0,
                                     (__attribute__((address_space(3))) u16*)bD0, 16, 0, 0);
    __builtin_amdgcn_global_load_lds((const __attribute__((address_space(1))) u16*)bS1,
                                     (__attribute__((address_space(3))) u16*)bD1, 16, 0, 0);
    aS0 += 32; aS1 += 32; bS0 += 32; bS1 += 32;
    __syncthreads();
    bf16x8 af[4], bfr[4];
#pragma unroll
    for (int i = 0; i < 4; i++) af[i] = *(const bf16x8*)(As + aOff[i]);
#pragma unroll
    for (int j = 0; j < 4; j++) bfr[j] = *(const bf16x8*)(Bs + bOff[j]);
#pragma unroll
    for (int i = 0; i < 4; i++)
#pragma unroll
      for (int j = 0; j < 4; j++)
        acc[i][j] = __builtin_amdgcn_mfma_f32_16x16x32_bf16(af[i], bfr[j], acc[i][j], 0, 0, 0);
    __syncthreads();
  }

  int cn = n0 + wn + (l & 15);
  int rm = m0 + wm + ((l >> 4) << 2);
#pragma unroll
  for (int j = 0; j < 4; j++) {
    int col = cn + j * 16;
    float bv = bias[col];
    bool doRelu = col < reluN;
#pragma unroll
    for (int i = 0; i < 4; i++)
#pragma unroll
      for (int r = 0; r < 4; r++) {
        float v = acc[i][j][r] + bv;
        v = doRelu ? fmaxf(v, 0.f) : v;
        C[(long)(rm + i * 16 + r) * N + col] = f2b(v);
      }
  }
}

__global__ __launch_bounds__(256) void gemm_l0(
    const u16* __restrict__ A, const u16* __restrict__ Bw, u16* __restrict__ C,
    const float* __restrict__ bias, int yOff) {
  gemm_body(A, Bw, C, bias, N0EXT, IN0, 12288, yOff);
}

__global__ __launch_bounds__(256) void gemm_l1(
    const u16* __restrict__ A, const u16* __restrict__ Bw, u16* __restrict__ C,
    const float* __restrict__ bias, int yOff) {
  int z = blockIdx.z;
  gemm_body(A + (long)z * 4096 * 512, Bw + (long)z * N1EXT * 512,
            C + (long)z * 4096 * N1EXT, bias + (long)z * N1EXT, N1EXT, 512, 2048, yOff);
}

// ================= 256x256 8-phase GEMM (m201-style template, plain HIP) ===========
// BM=BN=256, BK=64, 512 threads = 8 waves (2M x 4N), per-wave 128x64 output.
// LDS 128KB: A/B each [2 buf][2 half][128 rows][64 cols] bf16.
// Slot swizzle (both-sides involution): 16B slot s_phys = s_log ^ (row & 7)
//   -> staged via pre-swizzled GLOBAL source (global_load_lds dest stays linear),
//   -> ds_read_b128 conflict-free (2 lanes/bank).
// Counted vmcnt(2) only at end of phases 3/7; raw s_barrier (no vmcnt(0) drain).
#define GL_LDS(SRC, DST)                                                              \
  __builtin_amdgcn_global_load_lds((const __attribute__((address_space(1))) u16*)(SRC), \
                                   (__attribute__((address_space(3))) u16*)(DST), 16, 0, 0)
#define STG(PTR, DOFF)                     \
  do {                                     \
    GL_LDS((PTR), L + (DOFF) + tid * 8);   \
    (PTR) += 64;                           \
  } while (0)
#define FEN asm volatile("" ::: "memory")
#define BARR                        \
  do {                              \
    FEN;                            \
    __builtin_amdgcn_s_barrier();   \
    FEN;                            \
  } while (0)
#define VMW(N) asm volatile("s_waitcnt vmcnt(" #N ")" ::: "memory")

#define RD_A(BB, MH)                                                                      \
  _Pragma("unroll") for (int i = 0; i < 4; i++) {                                         \
    af[i][0] = *(const bf16x8*)(Lb + (BB) * 32768 + aFB + ((MH) * 4 + i) * 2048 + sp0);   \
    af[i][1] = *(const bf16x8*)(Lb + (BB) * 32768 + aFB + ((MH) * 4 + i) * 2048 + sp1);   \
  }
#define RD_B(BB, NH, ARR)                                                                 \
  _Pragma("unroll") for (int j = 0; j < 2; j++) {                                         \
    ARR[j][0] = *(const bf16x8*)(Lb + (BB) * 32768 + bFB + ((NH) * 2 + j) * 2048 + sp0);  \
    ARR[j][1] = *(const bf16x8*)(Lb + (BB) * 32768 + bFB + ((NH) * 2 + j) * 2048 + sp1);  \
  }
#define MMA(MH, NH, ARR)                                                                  \
  __builtin_amdgcn_s_setprio(1);                                                          \
  _Pragma("unroll") for (int i = 0; i < 4; i++)                                           \
  _Pragma("unroll") for (int j = 0; j < 2; j++) {                                         \
    acc[(MH) * 4 + i][(NH) * 2 + j] = __builtin_amdgcn_mfma_f32_16x16x32_bf16(            \
        af[i][0], ARR[j][0], acc[(MH) * 4 + i][(NH) * 2 + j], 0, 0, 0);                   \
    acc[(MH) * 4 + i][(NH) * 2 + j] = __builtin_amdgcn_mfma_f32_16x16x32_bf16(            \
        af[i][1], ARR[j][1], acc[(MH) * 4 + i][(NH) * 2 + j], 0, 0, 0);                   \
  }                                                                                       \
  __builtin_amdgcn_s_setprio(0)

template <bool FULL>
__device__ __forceinline__ void giter8(
    u16* L, const char* Lb, int tid,
    const u16* (&sAp)[2][2], const u16* (&sBp)[2][2],
    bf16x8 (&af)[4][2], bf16x8 (&bf0)[2][2], bf16x8 (&bf1)[2][2],
    floatx4 (&acc)[8][4], int aFB, int bFB, int sp0, int sp1) {
  // P0: buf0 (mh0,nh0); stage A[buf1] rb1 (tile 2i+1)
  RD_A(0, 0); RD_B(0, 0, bf0);
  STG(sAp[0][1], 20480); STG(sAp[1][1], 28672);
  BARR; MMA(0, 0, bf0); BARR;
  // P1: (mh0,nh1); stage B[buf1] rb0
  RD_B(0, 1, bf1);
  STG(sBp[0][0], 49152); STG(sBp[1][0], 57344);
  BARR; MMA(0, 1, bf1); BARR;
  // P2: (mh1,nh1); stage B[buf1] rb1
  RD_A(0, 1);
  STG(sBp[0][1], 53248); STG(sBp[1][1], 61440);
  BARR; MMA(1, 1, bf1); BARR;
  // P3: (mh1,nh0); stage A[buf0] rb0 (tile 2i+2); counted wait for buf1 residency
  if constexpr (FULL) { STG(sAp[0][0], 0); STG(sAp[1][0], 8192); }
  BARR; MMA(1, 0, bf0);
  if constexpr (FULL) { VMW(2); } else { VMW(0); }
  BARR;
  // P4: buf1 (mh0,nh0); stage B[buf0] rb0
  RD_A(1, 0); RD_B(1, 0, bf0);
  if constexpr (FULL) { STG(sBp[0][0], 32768); STG(sBp[1][0], 40960); }
  BARR; MMA(0, 0, bf0); BARR;
  // P5: (mh0,nh1); stage B[buf0] rb1
  RD_B(1, 1, bf1);
  if constexpr (FULL) { STG(sBp[0][1], 36864); STG(sBp[1][1], 45056); }
  BARR; MMA(0, 1, bf1); BARR;
  // P6: (mh1,nh1); stage A[buf0] rb1
  RD_A(1, 1);
  if constexpr (FULL) { STG(sAp[0][1], 4096); STG(sAp[1][1], 12288); }
  BARR; MMA(1, 1, bf1); BARR;
  // P7: (mh1,nh0); stage A[buf1] rb0 (tile 2i+3); counted wait for buf0 residency
  if constexpr (FULL) { STG(sAp[0][0], 16384); STG(sAp[1][0], 24576); }
  BARR; MMA(1, 0, bf0);
  if constexpr (FULL) { VMW(2); }
  BARR;
}

// C[m][n] = relu(sum_k A.B + bias[n]) over a 256x256 tile (expert columns only).
__device__ __forceinline__ void gemm256_body(
    const u16* __restrict__ A, const u16* __restrict__ Bw, u16* __restrict__ C,
    const float* __restrict__ bias, const int K, const int N, const int NIT) {
  __shared__ u16 L[65536];  // 128 KB
  const int tid = threadIdx.x;
  const int l = tid & 63, w = tid >> 6;
  const int wr = w >> 2, wc = w & 3;
  const int rl = l & 15;
  const int m0 = blockIdx.x * 256, n0 = blockIdx.y * 256;

  // staging: per-thread inverse-swizzled global source offset within a chunk
  const int srow = tid >> 3;                                  // 0..63 row in chunk
  const long stgOff = (long)srow * K + (((tid & 7) ^ (srow & 7)) * 8);
  const u16* sAp[2][2];
  const u16* sBp[2][2];
#pragma unroll
  for (int h = 0; h < 2; h++)
#pragma unroll
    for (int rb = 0; rb < 2; rb++) {
      sAp[h][rb] = A + (long)(m0 + h * 128 + rb * 64) * K + stgOff;
      sBp[h][rb] = Bw + (long)(n0 + h * 128 + rb * 64) * K + stgOff;
    }

  // prologue: tile0 (buf0) fully + tile1 A rb0; leave last pair in flight
  STG(sAp[0][0], 0);     STG(sAp[1][0], 8192);
  STG(sAp[0][1], 4096);  STG(sAp[1][1], 12288);
  STG(sBp[0][0], 32768); STG(sBp[1][0], 40960);
  STG(sBp[0][1], 36864); STG(sBp[1][1], 45056);
  STG(sAp[0][0], 16384); STG(sAp[1][0], 24576);

  const char* Lb = (const char*)L;
  const int aFB = wr * 16384 + rl * 128;
  const int bFB = 65536 + (wc >> 1) * 16384 + (wc & 1) * 8192 + rl * 128;
  const int sp0 = ((l >> 4) ^ (l & 7)) * 16;
  const int sp1 = (((l >> 4) + 4) ^ (l & 7)) * 16;

  floatx4 acc[8][4] = {};
  bf16x8 af[4][2], bf0[2][2], bf1[2][2];

  VMW(2);
  BARR;

  for (int it = 0; it < NIT - 1; ++it)
    giter8<true>(L, Lb, tid, sAp, sBp, af, bf0, bf1, acc, aFB, bFB, sp0, sp1);
  giter8<false>(L, Lb, tid, sAp, sBp, af, bf0, bf1, acc, aFB, bFB, sp0, sp1);

  // epilogue: bias + relu (all new-kernel columns are expert outputs)
  const int colB = n0 + wc * 64 + rl;
  const int rowB = m0 + wr * 128 + (l >> 4) * 4;
#pragma unroll
  for (int j = 0; j < 4; j++) {
    int col = colB + j * 16;
    float bv = bias[col];
#pragma unroll
    for (int i = 0; i < 8; i++)
#pragma unroll
      for (int r = 0; r < 4; r++) {
        float v = fmaxf(acc[i][j][r] + bv, 0.f);
        C[(long)(rowB + i * 16 + r) * N + col] = f2b(v);
      }
  }
}

__global__ __launch_bounds__(512, 2) void gemm_l0_256(
    const u16* __restrict__ A, const u16* __restrict__ Bw, u16* __restrict__ C,
    const float* __restrict__ bias) {
  gemm256_body(A, Bw, C, bias, 2176, N0EXT, 17);  // NT=34 K-tiles -> 17 iters
}

__global__ __launch_bounds__(512, 2) void gemm_l1_256(
    const u16* __restrict__ A, const u16* __restrict__ Bw, u16* __restrict__ C,
    const float* __restrict__ bias) {
  int z = blockIdx.z;
  gemm256_body(A + (long)z * 4096 * 512, Bw + (long)z * N1EXT * 512,
               C + (long)z * 4096 * N1EXT, bias + (long)z * N1EXT, 512, N1EXT, 4);
}

// ---------------- layer-0 softmax + mix: E0 [B][N0EXT] -> X1 [3][B][512] ----------
__global__ __launch_bounds__(256) void mix0_kernel(
    const u16* __restrict__ E0, u16* __restrict__ X1) {
  int b = blockIdx.x, tid = threadIdx.x;
  __shared__ float gw[56];
  const u16* row = E0 + (long)b * N0EXT;
  if (tid < 3) {
    int base = (tid == 0) ? 0 : (tid == 1) ? 16 : 32;
    int cnt = (tid == 2) ? 24 : 16;
    const u16* lg = row + 12288 + base;
    float mx = -1e30f;
    for (int i = 0; i < cnt; i++) mx = fmaxf(mx, b2f(lg[i]));
    float sum = 0.f;
    for (int i = 0; i < cnt; i++) {
      float e = __expf(b2f(lg[i]) - mx);
      gw[base + i] = e;
      sum += e;
    }
    float inv = 1.f / sum;
    for (int i = 0; i < cnt; i++) gw[base + i] *= inv;
  }
  __syncthreads();
#pragma unroll
  for (int half = 0; half < 2; half++) {
    int o = tid + half * 256;
    float t0 = 0.f, t1 = 0.f, s = 0.f;
#pragma unroll
    for (int e = 0; e < 8; e++) {
      float v0 = b2f(row[e * 512 + o]);
      float v1 = b2f(row[(8 + e) * 512 + o]);
      float vs = b2f(row[(16 + e) * 512 + o]);
      t0 = fmaf(gw[e], v0, t0);       t0 = fmaf(gw[8 + e], vs, t0);
      t1 = fmaf(gw[16 + e], v1, t1);  t1 = fmaf(gw[24 + e], vs, t1);
      s = fmaf(gw[32 + e], v0, s);
      s = fmaf(gw[40 + e], v1, s);
      s = fmaf(gw[48 + e], vs, s);
    }
    X1[((long)(0 * 4096 + b)) * 512 + o] = f2b(t0);
    X1[((long)(1 * 4096 + b)) * 512 + o] = f2b(t1);
    X1[((long)(2 * 4096 + b)) * 512 + o] = f2b(s);
  }
}

// ---------------- layer-1 softmax + mix: E1 [3][B][N1EXT] -> X2 [2][B][256] -------
__global__ __launch_bounds__(256) void mix1_kernel(
    const u16* __restrict__ E1, u16* __restrict__ X2) {
  int b = blockIdx.x, tid = threadIdx.x;
  __shared__ float gw[32];
  if (tid < 2) {
    const u16* lg = E1 + ((long)(tid * 4096 + b)) * N1EXT + 2048;
    float mx = -1e30f;
    for (int i = 0; i < 16; i++) mx = fmaxf(mx, b2f(lg[i]));
    float sum = 0.f;
    for (int i = 0; i < 16; i++) {
      float e = __expf(b2f(lg[i]) - mx);
      gw[tid * 16 + i] = e;
      sum += e;
    }
    float inv = 1.f / sum;
    for (int i = 0; i < 16; i++) gw[tid * 16 + i] *= inv;
  }
  __syncthreads();
  int o = tid;
  const u16* r0 = E1 + ((long)(0 * 4096 + b)) * N1EXT;
  const u16* r1 = E1 + ((long)(1 * 4096 + b)) * N1EXT;
  const u16* rs = E1 + ((long)(2 * 4096 + b)) * N1EXT;
  float t0 = 0.f, t1 = 0.f;
#pragma unroll
  for (int e = 0; e < 8; e++) {
    float vs = b2f(rs[e * 256 + o]);
    t0 = fmaf(gw[e], b2f(r0[e * 256 + o]), t0);
    t0 = fmaf(gw[8 + e], vs, t0);
    t1 = fmaf(gw[16 + e], b2f(r1[e * 256 + o]), t1);
    t1 = fmaf(gw[24 + e], vs, t1);
  }
  X2[((long)(0 * 4096 + b)) * 256 + o] = f2b(t0);
  X2[((long)(1 * 4096 + b)) * 256 + o] = f2b(t1);
}

// ---------------- fused towers: X2 --(K=256 MFMA)--> H1(LDS) --(K=128)--> H2(LDS)
// --> 64-dot + sigmoid -> out. grid (32,1,2): block = 128 rows of task z.
__global__ __launch_bounds__(256) void towers_fused(
    const u16* __restrict__ X2, const u16* __restrict__ TW0,
    const u16* __restrict__ TW1, const float* __restrict__ biasT0,
    const float* __restrict__ biasT1, const float* __restrict__ twoW,
    const float* __restrict__ twob, float* __restrict__ out) {
  __shared__ u16 As[128 * 32];
  __shared__ u16 Bs[128 * 32];
  __shared__ u16 Hs[128 * 136];  // padded rows: stride 136 u16 -> conflict-free frags
  int z = blockIdx.z;
  int tid = threadIdx.x;
  int m0 = blockIdx.x * 128;
  int l = tid & 63, w = tid >> 6;
  int wm = (w >> 1) * 64, wn = (w & 1) * 64;
  int q = l >> 4;

  const u16* A = X2 + (long)z * 4096 * 256;
  const u16* B0 = TW0 + (long)z * 128 * 256;
  const u16* B1 = TW1 + (long)z * 128 * 128;

  int aOff[4], bOff[4];
#pragma unroll
  for (int i = 0; i < 4; i++) {
    aOff[i] = (wm + i * 16 + (l & 15)) * 32 + q * 8;
    bOff[i] = (wn + i * 16 + (l & 15)) * 32 + q * 8;
  }
  int rmLoc = wm + (q << 2);
  int cnLoc = wn + (l & 15);

  // ---- tower layer 0: K=256 ----
  {
    const u16* aS0 = A + (long)(m0 + (tid >> 2)) * 256 + (tid & 3) * 8;
    const u16* aS1 = A + (long)(m0 + 64 + (tid >> 2)) * 256 + (tid & 3) * 8;
    const u16* bS0 = B0 + (long)(tid >> 2) * 256 + (tid & 3) * 8;
    const u16* bS1 = B0 + (long)(64 + (tid >> 2)) * 256 + (tid & 3) * 8;
    u16* aD0 = As + tid * 8;
    u16* aD1 = As + (256 + tid) * 8;
    u16* bD0 = Bs + tid * 8;
    u16* bD1 = Bs + (256 + tid) * 8;
    floatx4 acc[4][4] = {};
    for (int k0 = 0; k0 < 256; k0 += 32) {
      __builtin_amdgcn_global_load_lds((const __attribute__((address_space(1))) u16*)aS0,
                                       (__attribute__((address_space(3))) u16*)aD0, 16, 0, 0);
      __builtin_amdgcn_global_load_lds((const __attribute__((address_space(1))) u16*)aS1,
                                       (__attribute__((address_space(3))) u16*)aD1, 16, 0, 0);
      __builtin_amdgcn_global_load_lds((const __attribute__((address_space(1))) u16*)bS0,
                                       (__attribute__((address_space(3))) u16*)bD0, 16, 0, 0);
      __builtin_amdgcn_global_load_lds((const __attribute__((address_space(1))) u16*)bS1,
                                       (__attribute__((address_space(3))) u16*)bD1, 16, 0, 0);
      aS0 += 32; aS1 += 32; bS0 += 32; bS1 += 32;
      __syncthreads();
      bf16x8 af[4], bfr[4];
#pragma unroll
      for (int i = 0; i < 4; i++) af[i] = *(const bf16x8*)(As + aOff[i]);
#pragma unroll
      for (int j = 0; j < 4; j++) bfr[j] = *(const bf16x8*)(Bs + bOff[j]);
#pragma unroll
      for (int i = 0; i < 4; i++)
#pragma unroll
        for (int j = 0; j < 4; j++)
          acc[i][j] = __builtin_amdgcn_mfma_f32_16x16x32_bf16(af[i], bfr[j], acc[i][j], 0, 0, 0);
      __syncthreads();
    }
    // H1 -> LDS (relu + bias)
#pragma unroll
    for (int j = 0; j < 4; j++) {
      int col = cnLoc + j * 16;
      float bv = biasT0[z * 128 + col];
#pragma unroll
      for (int i = 0; i < 4; i++)
#pragma unroll
        for (int r = 0; r < 4; r++)
          Hs[(rmLoc + i * 16 + r) * 136 + col] = f2b(fmaxf(acc[i][j][r] + bv, 0.f));
    }
  }
  __syncthreads();

  // ---- tower layer 1: K=128, A from Hs ----
  floatx4 acc2[4][4] = {};
  {
    const u16* bS0 = B1 + (long)(tid >> 2) * 128 + (tid & 3) * 8;
    const u16* bS1 = B1 + (long)(64 + (tid >> 2)) * 128 + (tid & 3) * 8;
    u16* bD0 = Bs + tid * 8;
    u16* bD1 = Bs + (256 + tid) * 8;
    for (int k0 = 0; k0 < 128; k0 += 32) {
      __builtin_amdgcn_global_load_lds((const __attribute__((address_space(1))) u16*)bS0,
                                       (__attribute__((address_space(3))) u16*)bD0, 16, 0, 0);
      __builtin_amdgcn_global_load_lds((const __attribute__((address_space(1))) u16*)bS1,
                                       (__attribute__((address_space(3))) u16*)bD1, 16, 0, 0);
      bS0 += 32; bS1 += 32;
      __syncthreads();
      bf16x8 af[4], bfr[4];
#pragma unroll
      for (int i = 0; i < 4; i++)
        af[i] = *(const bf16x8*)(Hs + (wm + i * 16 + (l & 15)) * 136 + k0 + q * 8);
#pragma unroll
      for (int j = 0; j < 4; j++) bfr[j] = *(const bf16x8*)(Bs + bOff[j]);
#pragma unroll
      for (int i = 0; i < 4; i++)
#pragma unroll
        for (int j = 0; j < 4; j++)
          acc2[i][j] = __builtin_amdgcn_mfma_f32_16x16x32_bf16(af[i], bfr[j], acc2[i][j], 0, 0, 0);
      __syncthreads();
    }
  }
  // H2 -> LDS (relu + bias)
#pragma unroll
  for (int j = 0; j < 4; j++) {
    int col = cnLoc + j * 16;
    float bv = biasT1[z * 128 + col];
#pragma unroll
    for (int i = 0; i < 4; i++)
#pragma unroll
      for (int r = 0; r < 4; r++)
        Hs[(rmLoc + i * 16 + r) * 136 + col] = f2b(fmaxf(acc2[i][j][r] + bv, 0.f));
  }
  __syncthreads();

  // ---- final 64-dot + sigmoid ----
  if (tid < 128) {
    const float* wc = twoW + z * 64;
    const u16* xr = Hs + tid * 136;
    float acc = twob[z];
    for (int k = 0; k < 64; k++) acc = fmaf(b2f(xr[k]), wc[k], acc);
    out[z * 4096 + m0 + tid] = 1.f / (1.f + __expf(-acc));
  }
}

extern "C" void kernel_launch(void* const* d_in, const int* in_sizes, int n_in,
                              void* d_out, int out_size, void* d_ws, size_t ws_size,
                              hipStream_t stream) {
  const int* cat = (const int*)d_in[0];
  const float* numx = (const float*)d_in[1];
  const float* table = (const float*)d_in[2];
  const float* numW = (const float*)d_in[3];
  const float* numb = (const float*)d_in[4];
  const float* se0W = (const float*)d_in[5];
  const float* se0b = (const float*)d_in[6];
  const float* se0g = (const float*)d_in[7];
  const float* se0be = (const float*)d_in[8];
  const float* te0W = (const float*)d_in[9];
  const float* te0b = (const float*)d_in[10];
  const float* te0g = (const float*)d_in[11];
  const float* te0be = (const float*)d_in[12];
  const float* tg0W = (const float*)d_in[13];
  const float* tg0b = (const float*)d_in[14];
  const float* sg0W = (const float*)d_in[15];
  const float* sg0b = (const float*)d_in[16];
  const float* se1W = (const float*)d_in[17];
  const float* se1b = (const float*)d_in[18];
  const float* se1g = (const float*)d_in[19];
  const float* se1be = (const float*)d_in[20];
  const float* te1W = (const float*)d_in[21];
  const float* te1b = (const float*)d_in[22];
  const float* te1g = (const float*)d_in[23];
  const float* te1be = (const float*)d_in[24];
  const float* tg1W = (const float*)d_in[25];
  const float* tg1b = (const float*)d_in[26];
  const float* tw0W = (const float*)d_in[27];
  const float* tw0b = (const float*)d_in[28];
  const float* tw0g = (const float*)d_in[29];
  const float* tw0be = (const float*)d_in[30];
  const float* tw1W = (const float*)d_in[31];
  const float* tw1b = (const float*)d_in[32];
  const float* tw1g = (const float*)d_in[33];
  const float* tw1be = (const float*)d_in[34];
  const float* twoW = (const float*)d_in[35];
  const float* twob = (const float*)d_in[36];
  float* out = (float*)d_out;

  char* p = (char*)d_ws;
  u16* X0 = (u16*)p;        p += (size_t)4096 * IN0 * 2;
  u16* W0 = (u16*)p;        p += (size_t)N0EXT * IN0 * 2;
  float* bias0 = (float*)p; p += (size_t)N0EXT * 4;
  u16* X1 = (u16*)p;        p += (size_t)3 * 4096 * 512 * 2;
  u16* W1 = (u16*)p;        p += (size_t)3 * N1EXT * 512 * 2;
  float* bias1 = (float*)p; p += (size_t)3 * N1EXT * 4;
  u16* X2 = (u16*)p;        p += (size_t)2 * 4096 * 256 * 2;
  u16* TW0 = (u16*)p;       p += (size_t)2 * 128 * 256 * 2;
  float* biasT0 = (float*)p; p += (size_t)256 * 4;
  u16* TW1 = (u16*)p;       p += (size_t)2 * 128 * 128 * 2;
  float* biasT1 = (float*)p; p += (size_t)256 * 4;
  // big region, reused across phases: E0 -> E1
  u16* E0 = (u16*)p;  // 4096*N0EXT
  u16* E1 = (u16*)p;  // 3*4096*N1EXT  (E0 dead after mix0)

  input_build<<<10240, 256, 0, stream>>>(cat, table, numx, numW, numb, X0);
  repack_w_all<<<dim3(68, 16, 50), 256, 0, stream>>>(
      te0W, te0g, se0W, se0g, te1W, te1g, se1W, se1g, tw0W, tw0g, W0, W1, TW0);
  setup_small<<<713, 256, 0, stream>>>(
      tg0W, tg0b, sg0W, sg0b, tg1W, tg1b,
      te0b, te0g, te0be, se0b, se0g, se0be,
      te1b, te1g, te1be, se1b, se1g, se1be,
      tw0b, tw0g, tw0be, tw1W, tw1b, tw1g, tw1be,
      W0, W1, TW1, bias0, bias1, biasT0, biasT1);

  // PLE layer 0: 48x16 tiles of 256^2 (expert cols 0..12287) + gate panel (12288..12415)
  gemm_l0_256<<<dim3(16, 48), 512, 0, stream>>>(X0, W0, E0, bias0);
  gemm_l0<<<dim3(32, 1), 256, 0, stream>>>(X0, W0, E0, bias0, 96);
  mix0_kernel<<<4096, 256, 0, stream>>>(E0, X1);

  // PLE layer 1: 8x16 tiles of 256^2 per z (expert cols 0..2047) + gate panel (2048..2175)
  gemm_l1_256<<<dim3(16, 8, 3), 512, 0, stream>>>(X1, W1, E1, bias1);
  gemm_l1<<<dim3(32, 1, 3), 256, 0, stream>>>(X1, W1, E1, bias1, 16);
  mix1_kernel<<<4096, 256, 0, stream>>>(E1, X2);

  towers_fused<<<dim3(32, 1, 2), 256, 0, stream>>>(
      X2, TW0, TW1, biasT0, biasT1, twoW, twob, out);
}